// Round 4
// baseline (904.685 us; speedup 1.0000x reference)
//
#include <hip/hip_runtime.h>
#include <math.h>

#define BB 4
#define QQ 75
#define CC 640
#define HW 100
#define NWAY 5
#define KSHOT 5
#define MS 500
#define MSP 512
#define MTOT 7500
#define MPAD 7680     // 60 tiles of 128
#define TEMPER 2.0f
#define EPSN 1e-8f

typedef _Float16 v8h __attribute__((ext_vector_type(8)));
typedef float v4f __attribute__((ext_vector_type(4)));

__device__ inline void splitv(const float* x, v8h& hi, v8h& lo) {
#pragma unroll
    for (int j = 0; j < 8; ++j) {
        _Float16 h = (_Float16)x[j];
        float r0 = x[j] - (float)h;
        hi[j] = h; lo[j] = (_Float16)r0;
    }
}

typedef __attribute__((address_space(3))) unsigned int lds_uint;
typedef __attribute__((address_space(1))) const unsigned int glb_uint;
__device__ inline void gl_lds16(const void* g, void* l) {
    __builtin_amdgcn_global_load_lds((glb_uint*)g, (lds_uint*)l, 16, 0, 0);
}

// ---------------- qnorm: query inverse norms (coalesced, LDS-atomic) ----------
__global__ __launch_bounds__(256) void qnorm(const float* __restrict__ qx,
                                             float* __restrict__ invq) {
    int bq = blockIdx.x;
    const float* src = qx + (size_t)bq * CC * HW;
    __shared__ float ssq[HW];
    int t = threadIdx.x;
    for (int i = t; i < HW; i += 256) ssq[i] = 0.f;
    __syncthreads();
    for (int i = t; i < CC * HW; i += 256) { float v = src[i]; atomicAdd(&ssq[i % HW], v * v); }
    __syncthreads();
    if (t < HW) invq[bq * HW + t] = 1.f / (sqrtf(ssq[t]) + EPSN);
}

// ---------------- prep_A: qx -> Ahi/Alo (b, m=7680, c=640) f16, k-contiguous ----
__global__ __launch_bounds__(256) void prep_A(const float* __restrict__ qx,
                                              _Float16* __restrict__ Ahi,
                                              _Float16* __restrict__ Alo) {
    int bq = blockIdx.x;            // b*75+qi
    int b = bq / QQ, qi = bq % QQ;
    const float* src = qx + (size_t)bq * CC * HW;
    _Float16* dh = Ahi + ((size_t)b * MPAD + qi * HW) * CC;
    _Float16* dl = Alo + ((size_t)b * MPAD + qi * HW) * CC;
    __shared__ float tile[64 * HW];
    int t = threadIdx.x;
    for (int ct = 0; ct < 10; ++ct) {
        __syncthreads();
        const float* sp = src + (size_t)ct * 64 * HW;
        for (int i = t; i < 64 * HW; i += 256) tile[i] = sp[i];
        __syncthreads();
        for (int cell = t; cell < 800; cell += 256) {
            int p = cell >> 3, oct = cell & 7;
            float x[8];
#pragma unroll
            for (int j = 0; j < 8; ++j) x[j] = tile[(oct * 8 + j) * HW + p];
            v8h hi, lo; splitv(x, hi, lo);
            size_t off = (size_t)p * CC + ct * 64 + oct * 8;
            *(v8h*)(dh + off) = hi;
            *(v8h*)(dl + off) = lo;
        }
    }
}

// ---------------- prep_B: sup -> normalized Bhi/Blo (bw, n=512, c=640) f16 ------
__global__ __launch_bounds__(256) void prep_B(const float* __restrict__ sup,
                                              _Float16* __restrict__ Bhi,
                                              _Float16* __restrict__ Blo) {
    int bid = blockIdx.x;           // b*25+s
    int b = bid / 25, s = bid % 25, w = s / KSHOT, shot = s % KSHOT;
    const float* src = sup + (size_t)bid * CC * HW;
    __shared__ float ssq[HW];
    __shared__ float inv[HW];
    __shared__ float tile[64 * HW];
    int t = threadIdx.x;
    for (int i = t; i < HW; i += 256) ssq[i] = 0.f;
    __syncthreads();
    for (int i = t; i < CC * HW; i += 256) { float v = src[i]; atomicAdd(&ssq[i % HW], v * v); }
    __syncthreads();
    if (t < HW) inv[t] = 1.f / (sqrtf(ssq[t]) + EPSN);
    _Float16* dh = Bhi + ((size_t)(b * NWAY + w) * MSP + shot * HW) * CC;
    _Float16* dl = Blo + ((size_t)(b * NWAY + w) * MSP + shot * HW) * CC;
    for (int ct = 0; ct < 10; ++ct) {
        __syncthreads();
        const float* sp = src + (size_t)ct * 64 * HW;
        for (int i = t; i < 64 * HW; i += 256) tile[i] = sp[i];
        __syncthreads();
        for (int cell = t; cell < 800; cell += 256) {
            int p = cell >> 3, oct = cell & 7;
            float iv = inv[p];
            float x[8];
#pragma unroll
            for (int j = 0; j < 8; ++j) x[j] = tile[(oct * 8 + j) * HW + p] * iv;
            v8h hi, lo; splitv(x, hi, lo);
            size_t off = (size_t)p * CC + ct * 64 + oct * 8;
            *(v8h*)(dh + off) = hi;
            *(v8h*)(dl + off) = lo;
        }
    }
}

// ---------------- zero_pad: A rows [7500,7680), B rows [500,512) ----------------
__global__ void zero_pad(_Float16* Ahi, _Float16* Alo, _Float16* Bhi, _Float16* Blo) {
    int g = blockIdx.x * 256 + threadIdx.x;   // uint32 (2 f16) granularity
    if (g < 230400) {                          // A: 4 b * 180 rows * 320 uints
        int b = g / 57600, rem = g % 57600, r = rem / 320, c2 = rem % 320;
        size_t off = ((size_t)b * MPAD + MTOT + r) * (CC / 2) + c2;
        ((unsigned int*)Ahi)[off] = 0u;
        ((unsigned int*)Alo)[off] = 0u;
    } else if (g < 307200) {                   // B: 20 bw * 12 rows * 320 uints
        int h = g - 230400;
        int bw = h / 3840, rem = h % 3840, r = rem / 320, c2 = rem % 320;
        size_t off = ((size_t)bw * MSP + MS + r) * (CC / 2) + c2;
        ((unsigned int*)Bhi)[off] = 0u;
        ((unsigned int*)Blo)[off] = 0u;
    }
}

// ---------------- simkernel: DMA-staged fp16x3 MFMA + fused max/argmax ----------
// Grid: bid = (b*10 + nt)*60 + mt. Block 128m x 256n, 4 waves of 64x128.
// LDS cells (16B): AHI[512] @0, ALO @8K, BHI[1024] @16K, BLO @32K (48 KB).
// Cell (row,slot) holds k-octet (slot ^ ((row>>1)&3)) -> 2-way-max bank reads.
__global__ __launch_bounds__(256) void simkernel(
        const _Float16* __restrict__ Ahi, const _Float16* __restrict__ Alo,
        const _Float16* __restrict__ Bhi, const _Float16* __restrict__ Blo,
        float* __restrict__ pmax, int* __restrict__ pidx) {
    __shared__ char lds_raw[49152];
    v8h* LDSC = (v8h*)lds_raw;

    int bid = blockIdx.x;
    int mt = bid % 60; int t2 = bid / 60;
    int nt = t2 % 10;  int b = t2 / 10;
    int m0 = mt * 128;
    int w = nt >> 1, n0w = (nt & 1) * 256;

    int tid = threadIdx.x;
    int lane = tid & 63;
    int wvu = __builtin_amdgcn_readfirstlane(tid >> 6);

    const char* baseA[2] = {(const char*)(Ahi + ((size_t)b * MPAD + m0) * CC),
                            (const char*)(Alo + ((size_t)b * MPAD + m0) * CC)};
    const char* baseB[2] = {(const char*)(Bhi + ((size_t)(b * NWAY + w) * MSP + n0w) * CC),
                            (const char*)(Blo + ((size_t)(b * NWAY + w) * MSP + n0w) * CC)};

    // per-lane gather offset: row r=lane>>2, swizzled octet
    int rr0 = lane >> 2;
    int oct = (lane & 3) ^ ((lane >> 3) & 3);
    int laneoff = rr0 * (CC * 2) + oct * 16;

    const char* segsrc[12];
    char* segdst[12];
#pragma unroll
    for (int s = 0; s < 12; ++s) {
        int g = wvu * 12 + s;
        const char* base; int rowbase;
        if (g < 16) { base = baseA[g >> 3]; rowbase = (g & 7) * 16; }
        else { int h = g - 16; base = baseB[h >> 4]; rowbase = (h & 15) * 16; }
        segsrc[s] = base + (size_t)rowbase * (CC * 2);
        segdst[s] = lds_raw + g * 1024;
    }

    int wv = tid >> 6;
    int mrow_w = (wv >> 1) * 64;
    int ncol_w = (wv & 1) * 128;
    int lq = lane >> 4, lc = lane & 15;

    int idxA[4], idxB[8];
#pragma unroll
    for (int mf = 0; mf < 4; ++mf) {
        int row = mrow_w + mf * 16 + lc;
        idxA[mf] = row * 4 + (lq ^ ((row >> 1) & 3));
    }
#pragma unroll
    for (int nf = 0; nf < 8; ++nf) {
        int row = ncol_w + nf * 16 + lc;
        idxB[nf] = row * 4 + (lq ^ ((row >> 1) & 3));
    }
    v8h* AHI = LDSC;
    v8h* ALO = LDSC + 512;
    v8h* BHI = LDSC + 1024;
    v8h* BLO = LDSC + 2048;

    v4f acc[4][8];
#pragma unroll
    for (int mf = 0; mf < 4; ++mf)
#pragma unroll
        for (int nf = 0; nf < 8; ++nf) acc[mf][nf] = (v4f)0.f;

    for (int ch = 0; ch < 20; ++ch) {
        int choff = ch * 64;          // 32 f16 * 2 B
#pragma unroll
        for (int s = 0; s < 12; ++s)
            gl_lds16(segsrc[s] + choff + laneoff, segdst[s]);
        __syncthreads();              // vmcnt drain + barrier: LDS ready

        v8h ahi[4], alo[4];
#pragma unroll
        for (int mf = 0; mf < 4; ++mf) { ahi[mf] = AHI[idxA[mf]]; alo[mf] = ALO[idxA[mf]]; }
#pragma unroll
        for (int nf = 0; nf < 8; ++nf) {
            v8h bhi = BHI[idxB[nf]], blo = BLO[idxB[nf]];
#pragma unroll
            for (int mf = 0; mf < 4; ++mf) {
                acc[mf][nf] = __builtin_amdgcn_mfma_f32_16x16x32_f16(ahi[mf], bhi, acc[mf][nf], 0, 0, 0);
                acc[mf][nf] = __builtin_amdgcn_mfma_f32_16x16x32_f16(ahi[mf], blo, acc[mf][nf], 0, 0, 0);
                acc[mf][nf] = __builtin_amdgcn_mfma_f32_16x16x32_f16(alo[mf], bhi, acc[mf][nf], 0, 0, 0);
            }
        }
        __syncthreads();              // all waves done reading before next DMA
    }

    int chunkidx = (nt & 1) * 2 + (wv & 1);     // ascending n within the way
#pragma unroll
    for (int mf = 0; mf < 4; ++mf) {
#pragma unroll
        for (int r = 0; r < 4; ++r) {
            float v = -__builtin_inff(); int idx = 0x7fffffff;
#pragma unroll
            for (int nf = 0; nf < 8; ++nf) {
                int n_way = n0w + ncol_w + nf * 16 + lc;
                float cv = acc[mf][nf][r];
                if (n_way < MS && cv > v) { v = cv; idx = n_way; }
            }
#pragma unroll
            for (int msk = 1; msk < 16; msk <<= 1) {
                float ov = __shfl_xor(v, msk);
                int oi = __shfl_xor(idx, msk);
                if (ov > v || (ov == v && oi < idx)) { v = ov; idx = oi; }
            }
            if (lc == 0) {
                int mrow = m0 + mrow_w + mf * 16 + lq * 4 + r;
                size_t o = ((size_t)(b * NWAY + w) * 4 + chunkidx) * MPAD + mrow;
                pmax[o] = v; pidx[o] = idx;
            }
        }
    }
}

// ================= FALLBACK PATH (ws too small): R3 kernels =================
__global__ void norm_support(const float* __restrict__ sup, float* __restrict__ snre) {
    int bid = blockIdx.x;
    int b = bid / 25, s = bid % 25;
    int w = s / KSHOT, shot = s % KSHOT;
    const float* src = sup + (size_t)bid * CC * HW;
    float* dst = snre + ((size_t)(b * NWAY + w)) * CC * MSP + shot * HW;
    __shared__ float inv[HW];
    int t = threadIdx.x;
    if (t < HW) {
        float ss = 0.f;
        for (int c = 0; c < CC; ++c) { float v = src[c * HW + t]; ss += v * v; }
        inv[t] = 1.f / (sqrtf(ss) + EPSN);
    }
    __syncthreads();
    for (int i = t; i < CC * HW; i += 256) {
        int c = i / HW, p = i % HW;
        dst[c * MSP + p] = src[i] * inv[p];
    }
    if (shot == KSHOT - 1) {
        float* padbase = snre + ((size_t)(b * NWAY + w)) * CC * MSP;
        for (int i = t; i < CC * (MSP - MS); i += 256) {
            int c = i / (MSP - MS), j = i % (MSP - MS);
            padbase[c * MSP + MS + j] = 0.f;
        }
    }
}

__global__ __launch_bounds__(256) void simkernel_fb(
        const float* __restrict__ qx, const float* __restrict__ snre,
        float* __restrict__ pmax, int* __restrict__ pidx) {
    __shared__ char lds_raw[49152];
    v8h* AHI = (v8h*)(lds_raw);
    v8h* ALO = (v8h*)(lds_raw + 8192);
    v8h* BHI = (v8h*)(lds_raw + 16384);
    v8h* BLO = (v8h*)(lds_raw + 32768);

    int bid = blockIdx.x;
    int mt = bid % 60; int t2 = bid / 60;
    int nt = t2 % 10;  int b = t2 / 10;
    int m0 = mt * 128;
    int w = nt >> 1;
    int n0w = (nt & 1) * 256;

    int tid = threadIdx.x;
    const float* Abase = qx + (size_t)b * QQ * CC * HW;
    const float* Bbase = snre + (size_t)(b * NWAY + w) * CC * MSP;

    int oct = tid & 3;
    int arow = tid >> 2;
    int aqi[2], ap[2];
#pragma unroll
    for (int pass = 0; pass < 2; ++pass) {
        int mg = m0 + arow + pass * 64;
        if (mg >= MTOT) mg = 0;
        aqi[pass] = mg / HW; ap[pass] = mg % HW;
    }

    v4f acc[4][8];
#pragma unroll
    for (int mf = 0; mf < 4; ++mf)
#pragma unroll
        for (int nf = 0; nf < 8; ++nf) acc[mf][nf] = (v4f)0.f;

    int lane = tid & 63;
    int wv = tid >> 6;
    int mrow_w = (wv >> 1) * 64;
    int ncol_w = (wv & 1) * 128;
    int lq = lane >> 4, lc = lane & 15;

    for (int ch = 0; ch < 20; ++ch) {
        int c0 = ch * 32 + oct * 8;
        __syncthreads();
#pragma unroll
        for (int pass = 0; pass < 2; ++pass) {
            const float* src = Abase + ((size_t)aqi[pass] * CC + c0) * HW + ap[pass];
            float x[8];
#pragma unroll
            for (int j = 0; j < 8; ++j) x[j] = src[j * HW];
            v8h hi, lo; splitv(x, hi, lo);
            int cell = (arow + pass * 64) * 4 + oct;
            AHI[cell] = hi; ALO[cell] = lo;
        }
#pragma unroll
        for (int pass = 0; pass < 4; ++pass) {
            int nrow = arow + pass * 64;
            const float* src = Bbase + (size_t)c0 * MSP + n0w + nrow;
            float x[8];
#pragma unroll
            for (int j = 0; j < 8; ++j) x[j] = src[j * MSP];
            v8h hi, lo; splitv(x, hi, lo);
            int cell = nrow * 4 + oct;
            BHI[cell] = hi; BLO[cell] = lo;
        }
        __syncthreads();

        v8h ahi[4], alo[4];
#pragma unroll
        for (int mf = 0; mf < 4; ++mf) {
            int idx = (mrow_w + mf * 16 + lc) * 4 + lq;
            ahi[mf] = AHI[idx]; alo[mf] = ALO[idx];
        }
#pragma unroll
        for (int nf = 0; nf < 8; ++nf) {
            int idx = (ncol_w + nf * 16 + lc) * 4 + lq;
            v8h bhi = BHI[idx], blo = BLO[idx];
#pragma unroll
            for (int mf = 0; mf < 4; ++mf) {
                acc[mf][nf] = __builtin_amdgcn_mfma_f32_16x16x32_f16(ahi[mf], bhi, acc[mf][nf], 0, 0, 0);
                acc[mf][nf] = __builtin_amdgcn_mfma_f32_16x16x32_f16(ahi[mf], blo, acc[mf][nf], 0, 0, 0);
                acc[mf][nf] = __builtin_amdgcn_mfma_f32_16x16x32_f16(alo[mf], bhi, acc[mf][nf], 0, 0, 0);
            }
        }
    }

    int chunkidx = (nt & 1) * 2 + (wv & 1);
#pragma unroll
    for (int mf = 0; mf < 4; ++mf) {
#pragma unroll
        for (int r = 0; r < 4; ++r) {
            float v = -__builtin_inff(); int idx = 0x7fffffff;
#pragma unroll
            for (int nf = 0; nf < 8; ++nf) {
                int n_way = n0w + ncol_w + nf * 16 + lc;
                float cv = acc[mf][nf][r];
                if (n_way < MS && cv > v) { v = cv; idx = n_way; }
            }
#pragma unroll
            for (int msk = 1; msk < 16; msk <<= 1) {
                float ov = __shfl_xor(v, msk);
                int oi = __shfl_xor(idx, msk);
                if (ov > v || (ov == v && oi < idx)) { v = ov; idx = oi; }
            }
            if (lc == 0) {
                int mrow = m0 + mrow_w + mf * 16 + lq * 4 + r;
                size_t o = ((size_t)(b * NWAY + w) * 4 + chunkidx) * MPAD + mrow;
                pmax[o] = v; pidx[o] = idx;
            }
        }
    }
}

// ---------------- combine 4 n-chunks, apply invq ----------------
__global__ void combine(const float* __restrict__ pmax, const int* __restrict__ pidx,
                        const float* __restrict__ invq,
                        float* __restrict__ smax, int* __restrict__ sidx) {
    int g = blockIdx.x * 256 + threadIdx.x;
    if (g >= BB * NWAY * MTOT) return;
    int m = g % MTOT; int t = g / MTOT;
    int w = t % NWAY, b = t / NWAY;
    size_t base = ((size_t)(b * NWAY + w) * 4) * MPAD + m;
    float best = pmax[base]; int bi = pidx[base];
#pragma unroll
    for (int c = 1; c < 4; ++c) {
        float v = pmax[base + (size_t)c * MPAD];
        int ii = pidx[base + (size_t)c * MPAD];
        if (v > best) { best = v; bi = ii; }
    }
    int qi = m / HW, p = m % HW;
    size_t o = ((size_t)(b * QQ + qi) * NWAY + w) * HW + p;
    smax[o] = best * invq[b * MTOT + m];
    sidx[o] = bi;
}

// ---------------- finalize ----------------
__global__ void finalize(const float* __restrict__ smax, const int* __restrict__ sidx,
                         const int* __restrict__ qy, float* __restrict__ lossi) {
    int bq = blockIdx.x;
    __shared__ float sm[NWAY][HW];
    __shared__ int   si[NWAY][HW];
    __shared__ float diffv[HW];
    __shared__ int   nearest[HW];
    __shared__ float maskv[HW];
    __shared__ float pred[NWAY];
    int t = threadIdx.x;
    for (int i = t; i < NWAY * HW; i += blockDim.x) {
        sm[i / HW][i % HW] = smax[(size_t)bq * NWAY * HW + i];
        si[i / HW][i % HW] = sidx[(size_t)bq * NWAY * HW + i];
    }
    __syncthreads();
    if (t < HW) {
        float v1 = -INFINITY, v2 = -INFINITY;
        float bestv = -INFINITY; int bestslot = 0;
        for (int w = 0; w < NWAY; ++w) {
            float v = sm[w][t];
            if (v > v1) { v2 = v1; v1 = v; } else if (v > v2) { v2 = v; }
            if (v > bestv) { bestv = v; bestslot = w * MS + si[w][t]; }
        }
        diffv[t] = v1 - v2;
        nearest[t] = bestslot;
    }
    __syncthreads();
    if (t < HW) {
        int slot = nearest[t];
        float bv = (nearest[0] == slot) ? diffv[0] : 0.f;
        int bm = 0;
        for (int m = 1; m < HW; ++m) {
            float val = (nearest[m] == slot) ? diffv[m] : 0.f;
            if (val > bv) { bv = val; bm = m; }
        }
        maskv[t] = (bm == t) ? TEMPER : 0.f;
    }
    __syncthreads();
    if (t < NWAY) {
        float s = 0.f;
        for (int m = 0; m < HW; ++m) s += sm[t][m] * maskv[m];
        pred[t] = s;
    }
    __syncthreads();
    if (t == 0) {
        float mx = pred[0];
        for (int w = 1; w < NWAY; ++w) mx = fmaxf(mx, pred[w]);
        float se = 0.f;
        for (int w = 0; w < NWAY; ++w) se += expf(pred[w] - mx);
        float lse = mx + logf(se);
        int y = qy[bq];
        lossi[bq] = -(pred[y] - lse);
    }
}

__global__ void reduce_loss(const float* __restrict__ lossi, float* __restrict__ out) {
    int t = threadIdx.x;
    float v = 0.f;
    for (int i = t; i < BB * QQ; i += 64) v += lossi[i];
    for (int m = 32; m > 0; m >>= 1) v += __shfl_xor(v, m);
    if (t == 0) out[0] = v / (float)(BB * QQ);
}

extern "C" void kernel_launch(void* const* d_in, const int* in_sizes, int n_in,
                              void* d_out, int out_size, void* d_ws, size_t ws_size,
                              hipStream_t stream) {
    const float* sup = (const float*)d_in[0];   // support_xf (4,25,640,10,10) f32
    const float* qx  = (const float*)d_in[2];   // query_xf   (4,75,640,10,10) f32
    const int*   qy  = (const int*)d_in[3];     // query_y    (4,75) int32
    float* out = (float*)d_out;

    // header region (~6.2 MB)
    float* pmax = (float*)d_ws;                                 // 614400 f
    int*   pidx = (int*)(pmax + (size_t)BB * NWAY * 4 * MPAD);
    float* smax = (float*)(pidx + (size_t)BB * NWAY * 4 * MPAD);
    int*   sidx = (int*)(smax + (size_t)BB * QQ * NWAY * HW);
    float* invq = (float*)(sidx + (size_t)BB * QQ * NWAY * HW);
    float* lossi = invq + (size_t)BB * MTOT;
    char*  big = (char*)(lossi + 512);
    size_t header = (size_t)(big - (char*)d_ws);
    size_t needA = (size_t)BB * MPAD * CC * 2;    // 39.3 MB per array
    size_t needB = (size_t)BB * NWAY * MSP * CC * 2;  // 13.1 MB per array
    size_t need_fast = header + 2 * (needA + needB);

    hipLaunchKernelGGL(qnorm, dim3(BB * QQ), dim3(256), 0, stream, qx, invq);

    if (ws_size >= need_fast) {
        _Float16* Ahi = (_Float16*)big;
        _Float16* Alo = Ahi + (size_t)BB * MPAD * CC;
        _Float16* Bhi = Alo + (size_t)BB * MPAD * CC;
        _Float16* Blo = Bhi + (size_t)BB * NWAY * MSP * CC;
        hipLaunchKernelGGL(prep_A, dim3(BB * QQ), dim3(256), 0, stream, qx, Ahi, Alo);
        hipLaunchKernelGGL(prep_B, dim3(BB * 25), dim3(256), 0, stream, sup, Bhi, Blo);
        hipLaunchKernelGGL(zero_pad, dim3(1200), dim3(256), 0, stream, Ahi, Alo, Bhi, Blo);
        hipLaunchKernelGGL(simkernel, dim3(BB * 10 * 60), dim3(256), 0, stream,
                           Ahi, Alo, Bhi, Blo, pmax, pidx);
    } else {
        float* snre = (float*)big;   // 26.2 MB
        hipLaunchKernelGGL(norm_support, dim3(BB * 25), dim3(256), 0, stream, sup, snre);
        hipLaunchKernelGGL(simkernel_fb, dim3(BB * 10 * 60), dim3(256), 0, stream,
                           qx, snre, pmax, pidx);
    }
    hipLaunchKernelGGL(combine, dim3((BB * NWAY * MTOT + 255) / 256), dim3(256), 0, stream,
                       pmax, pidx, invq, smax, sidx);
    hipLaunchKernelGGL(finalize, dim3(BB * QQ), dim3(128), 0, stream, smax, sidx, qy, lossi);
    hipLaunchKernelGGL(reduce_loss, dim3(1), dim3(64), 0, stream, lossi, out);
}

// Round 6
// 702.215 us; speedup vs baseline: 1.2883x; 1.2883x over previous
//
#include <hip/hip_runtime.h>
#include <math.h>

#define BB 4
#define QQ 75
#define CC 640
#define HW 100
#define NWAY 5
#define KSHOT 5
#define MS 500
#define MSP 512
#define MTOT 7500
#define MPAD 7680     // 60 tiles of 128
#define TEMPER 2.0f
#define EPSN 1e-8f
#define LDSBUF 49152

typedef _Float16 v8h __attribute__((ext_vector_type(8)));
typedef float v4f __attribute__((ext_vector_type(4)));

__device__ inline void splitv(const float* x, v8h& hi, v8h& lo) {
#pragma unroll
    for (int j = 0; j < 8; ++j) {
        _Float16 h = (_Float16)x[j];
        float r0 = x[j] - (float)h;
        hi[j] = h; lo[j] = (_Float16)r0;
    }
}

typedef __attribute__((address_space(3))) unsigned int lds_uint;
typedef __attribute__((address_space(1))) const unsigned int glb_uint;
__device__ inline void gl_lds16(const void* g, void* l) {
    __builtin_amdgcn_global_load_lds((glb_uint*)g, (lds_uint*)l, 16, 0, 0);
}

// ---------------- norms: inverse channel-norms for query (300) + support (100) ----
__global__ __launch_bounds__(256) void norms(const float* __restrict__ qx,
                                             const float* __restrict__ sup,
                                             float* __restrict__ invq,
                                             float* __restrict__ invs) {
    int bid = blockIdx.x;           // 0..399
    const float* src; float* dst;
    if (bid < BB * QQ) { src = qx + (size_t)bid * CC * HW; dst = invq + bid * HW; }
    else { int bs = bid - BB * QQ; src = sup + (size_t)bs * CC * HW; dst = invs + bs * HW; }
    __shared__ float ssq[HW];
    int t = threadIdx.x;
    for (int i = t; i < HW; i += 256) ssq[i] = 0.f;
    __syncthreads();
    for (int i = t; i < CC * HW; i += 256) { float v = src[i]; atomicAdd(&ssq[i % HW], v * v); }
    __syncthreads();
    if (t < HW) dst[t] = 1.f / (sqrtf(ssq[t]) + EPSN);
}

// ---------------- prep_AB: transpose+split one 64-channel chunk per block --------
// g < 3000: A (bq, ct) raw query -> Ahi/Alo (b, m, c) f16 k-contiguous
// g >= 3000: B (bs, ct) normalized support -> Bhi/Blo (bw, n, c)
__global__ __launch_bounds__(256) void prep_AB(const float* __restrict__ qx,
                                               const float* __restrict__ sup,
                                               const float* __restrict__ invs,
                                               _Float16* __restrict__ Ahi,
                                               _Float16* __restrict__ Alo,
                                               _Float16* __restrict__ Bhi,
                                               _Float16* __restrict__ Blo) {
    int g = blockIdx.x;
    const float* src; const float* inv = 0;
    _Float16 *dh, *dl;
    int ct;
    if (g < BB * QQ * 10) {
        int bq = g / 10; ct = g % 10;
        int b = bq / QQ, qi = bq % QQ;
        src = qx + ((size_t)bq * CC + ct * 64) * HW;
        size_t rowbase = (size_t)b * MPAD + qi * HW;
        dh = Ahi + rowbase * CC; dl = Alo + rowbase * CC;
    } else {
        int h = g - BB * QQ * 10;
        int bs = h / 10; ct = h % 10;
        int b = bs / 25, s = bs % 25, w = s / KSHOT, shot = s % KSHOT;
        src = sup + ((size_t)bs * CC + ct * 64) * HW;
        size_t rowbase = (size_t)(b * NWAY + w) * MSP + shot * HW;
        dh = Bhi + rowbase * CC; dl = Blo + rowbase * CC;
        inv = invs + bs * HW;
    }
    __shared__ float tile[64 * 101];   // padded stride 101: transpose reads 2-way max
    __shared__ float invt[HW];
    int t = threadIdx.x;
    if (t < HW) invt[t] = inv ? inv[t] : 1.f;
    for (int i = t; i < 64 * HW; i += 256) tile[(i / HW) * 101 + (i % HW)] = src[i];
    __syncthreads();
    for (int cell = t; cell < 800; cell += 256) {
        int p = cell >> 3, oct = cell & 7;
        float iv = invt[p];
        float x[8];
#pragma unroll
        for (int j = 0; j < 8; ++j) x[j] = tile[(oct * 8 + j) * 101 + p] * iv;
        v8h hi, lo; splitv(x, hi, lo);
        size_t off = (size_t)p * CC + ct * 64 + oct * 8;
        *(v8h*)(dh + off) = hi;
        *(v8h*)(dl + off) = lo;
    }
}

// ---------------- zero_pad: A rows [7500,7680), B rows [500,512) ----------------
__global__ void zero_pad(_Float16* Ahi, _Float16* Alo, _Float16* Bhi, _Float16* Blo) {
    int g = blockIdx.x * 256 + threadIdx.x;   // uint32 (2 f16) granularity
    if (g < 230400) {                          // A: 4 b * 180 rows * 320 uints
        int b = g / 57600, rem = g % 57600, r = rem / 320, c2 = rem % 320;
        size_t off = ((size_t)b * MPAD + MTOT + r) * (CC / 2) + c2;
        ((unsigned int*)Ahi)[off] = 0u;
        ((unsigned int*)Alo)[off] = 0u;
    } else if (g < 307200) {                   // B: 20 bw * 12 rows * 320 uints
        int h = g - 230400;
        int bw = h / 3840, rem = h % 3840, r = rem / 320, c2 = rem % 320;
        size_t off = ((size_t)bw * MSP + MS + r) * (CC / 2) + c2;
        ((unsigned int*)Bhi)[off] = 0u;
        ((unsigned int*)Blo)[off] = 0u;
    }
}

// ---------------- simkernel: double-buffered DMA fp16x3 MFMA + fused max/argmax --
// Grid: bid = (b*10 + nt)*60 + mt. Block 128m x 256n, 4 waves of 64x128.
// One 96 KB LDS block, two 48 KB halves selected by byte offset (no LDS pointer
// arrays -> avoids addrspacecast-in-initializer). DMA(ch+1) issued BEFORE
// compute(ch) so the vmcnt(0) drain at the next barrier finds loads complete.
__global__ __launch_bounds__(256, 1) void simkernel(
        const _Float16* __restrict__ Ahi, const _Float16* __restrict__ Alo,
        const _Float16* __restrict__ Bhi, const _Float16* __restrict__ Blo,
        float* __restrict__ pmax, int* __restrict__ pidx) {
    __shared__ char lds_raw[2 * LDSBUF];

    int bid = blockIdx.x;
    int mt = bid % 60; int t2 = bid / 60;
    int nt = t2 % 10;  int b = t2 / 10;
    int m0 = mt * 128;
    int w = nt >> 1, n0w = (nt & 1) * 256;

    int tid = threadIdx.x;
    int lane = tid & 63;
    int wvu = __builtin_amdgcn_readfirstlane(tid >> 6);

    const char* baseA[2] = {(const char*)(Ahi + ((size_t)b * MPAD + m0) * CC),
                            (const char*)(Alo + ((size_t)b * MPAD + m0) * CC)};
    const char* baseB[2] = {(const char*)(Bhi + ((size_t)(b * NWAY + w) * MSP + n0w) * CC),
                            (const char*)(Blo + ((size_t)(b * NWAY + w) * MSP + n0w) * CC)};

    // per-lane gather: row r=lane>>2 within 16-row segment, swizzled octet
    int rr0 = lane >> 2;
    int oct = (lane & 3) ^ ((lane >> 3) & 3);
    int laneoff = rr0 * (CC * 2) + oct * 16;

    const char* segsrc[12];
    int segoff[12];
#pragma unroll
    for (int s = 0; s < 12; ++s) {
        int g = wvu * 12 + s;
        const char* base; int rowbase;
        if (g < 16) { base = baseA[g >> 3]; rowbase = (g & 7) * 16; }
        else { int h = g - 16; base = baseB[h >> 4]; rowbase = (h & 15) * 16; }
        segsrc[s] = base + (size_t)rowbase * (CC * 2) + laneoff;
        segoff[s] = g * 1024;
    }

    int wv = tid >> 6;
    int mrow_w = (wv >> 1) * 64;
    int ncol_w = (wv & 1) * 128;
    int lq = lane >> 4, lc = lane & 15;

    int idxA[4], idxB[8];
#pragma unroll
    for (int mf = 0; mf < 4; ++mf) {
        int row = mrow_w + mf * 16 + lc;
        idxA[mf] = row * 4 + (lq ^ ((row >> 1) & 3));
    }
#pragma unroll
    for (int nf = 0; nf < 8; ++nf) {
        int row = ncol_w + nf * 16 + lc;
        idxB[nf] = row * 4 + (lq ^ ((row >> 1) & 3));
    }

    v4f acc[4][8];
#pragma unroll
    for (int mf = 0; mf < 4; ++mf)
#pragma unroll
        for (int nf = 0; nf < 8; ++nf) acc[mf][nf] = (v4f)0.f;

    // prologue: DMA chunk 0 into buffer half 0
#pragma unroll
    for (int s = 0; s < 12; ++s)
        gl_lds16(segsrc[s], lds_raw + segoff[s]);

    for (int ch = 0; ch < 20; ++ch) {
        __syncthreads();              // drains DMA(ch); also fences compute(ch-1) reads
        if (ch < 19) {                // prefetch next chunk into the other half
            int choff = (ch + 1) * 64;
            int dbase = ((ch + 1) & 1) * LDSBUF;
#pragma unroll
            for (int s = 0; s < 12; ++s)
                gl_lds16(segsrc[s] + choff, lds_raw + dbase + segoff[s]);
        }
        char* cbuf = lds_raw + (ch & 1) * LDSBUF;
        v8h* AHI = (v8h*)cbuf;
        v8h* ALO = (v8h*)(cbuf + 8192);
        v8h* BHI = (v8h*)(cbuf + 16384);
        v8h* BLO = (v8h*)(cbuf + 32768);

        v8h ahi[4], alo[4];
#pragma unroll
        for (int mf = 0; mf < 4; ++mf) { ahi[mf] = AHI[idxA[mf]]; alo[mf] = ALO[idxA[mf]]; }
#pragma unroll
        for (int nf = 0; nf < 8; ++nf) {
            v8h bhi = BHI[idxB[nf]], blo = BLO[idxB[nf]];
#pragma unroll
            for (int mf = 0; mf < 4; ++mf) {
                acc[mf][nf] = __builtin_amdgcn_mfma_f32_16x16x32_f16(ahi[mf], bhi, acc[mf][nf], 0, 0, 0);
                acc[mf][nf] = __builtin_amdgcn_mfma_f32_16x16x32_f16(ahi[mf], blo, acc[mf][nf], 0, 0, 0);
                acc[mf][nf] = __builtin_amdgcn_mfma_f32_16x16x32_f16(alo[mf], bhi, acc[mf][nf], 0, 0, 0);
            }
        }
    }

    int chunkidx = (nt & 1) * 2 + (wv & 1);     // ascending n within the way
#pragma unroll
    for (int mf = 0; mf < 4; ++mf) {
#pragma unroll
        for (int r = 0; r < 4; ++r) {
            float v = -__builtin_inff(); int idx = 0x7fffffff;
#pragma unroll
            for (int nf = 0; nf < 8; ++nf) {
                int n_way = n0w + ncol_w + nf * 16 + lc;
                float cv = acc[mf][nf][r];
                if (n_way < MS && cv > v) { v = cv; idx = n_way; }
            }
#pragma unroll
            for (int msk = 1; msk < 16; msk <<= 1) {
                float ov = __shfl_xor(v, msk);
                int oi = __shfl_xor(idx, msk);
                if (ov > v || (ov == v && oi < idx)) { v = ov; idx = oi; }
            }
            if (lc == 0) {
                int mrow = m0 + mrow_w + mf * 16 + lq * 4 + r;
                size_t o = ((size_t)(b * NWAY + w) * 4 + chunkidx) * MPAD + mrow;
                pmax[o] = v; pidx[o] = idx;
            }
        }
    }
}

// ================= FALLBACK PATH (ws too small): R3 kernels =================
__global__ void norm_support(const float* __restrict__ sup, float* __restrict__ snre) {
    int bid = blockIdx.x;
    int b = bid / 25, s = bid % 25;
    int w = s / KSHOT, shot = s % KSHOT;
    const float* src = sup + (size_t)bid * CC * HW;
    float* dst = snre + ((size_t)(b * NWAY + w)) * CC * MSP + shot * HW;
    __shared__ float inv[HW];
    int t = threadIdx.x;
    if (t < HW) {
        float ss = 0.f;
        for (int c = 0; c < CC; ++c) { float v = src[c * HW + t]; ss += v * v; }
        inv[t] = 1.f / (sqrtf(ss) + EPSN);
    }
    __syncthreads();
    for (int i = t; i < CC * HW; i += 256) {
        int c = i / HW, p = i % HW;
        dst[c * MSP + p] = src[i] * inv[p];
    }
    if (shot == KSHOT - 1) {
        float* padbase = snre + ((size_t)(b * NWAY + w)) * CC * MSP;
        for (int i = t; i < CC * (MSP - MS); i += 256) {
            int c = i / (MSP - MS), j = i % (MSP - MS);
            padbase[c * MSP + MS + j] = 0.f;
        }
    }
}

__global__ __launch_bounds__(256) void simkernel_fb(
        const float* __restrict__ qx, const float* __restrict__ snre,
        float* __restrict__ pmax, int* __restrict__ pidx) {
    __shared__ char lds_fb[49152];
    v8h* AHI = (v8h*)(lds_fb);
    v8h* ALO = (v8h*)(lds_fb + 8192);
    v8h* BHI = (v8h*)(lds_fb + 16384);
    v8h* BLO = (v8h*)(lds_fb + 32768);

    int bid = blockIdx.x;
    int mt = bid % 60; int t2 = bid / 60;
    int nt = t2 % 10;  int b = t2 / 10;
    int m0 = mt * 128;
    int w = nt >> 1;
    int n0w = (nt & 1) * 256;

    int tid = threadIdx.x;
    const float* Abase = qx + (size_t)b * QQ * CC * HW;
    const float* Bbase = snre + (size_t)(b * NWAY + w) * CC * MSP;

    int oct = tid & 3;
    int arow = tid >> 2;
    int aqi[2], ap[2];
#pragma unroll
    for (int pass = 0; pass < 2; ++pass) {
        int mg = m0 + arow + pass * 64;
        if (mg >= MTOT) mg = 0;
        aqi[pass] = mg / HW; ap[pass] = mg % HW;
    }

    v4f acc[4][8];
#pragma unroll
    for (int mf = 0; mf < 4; ++mf)
#pragma unroll
        for (int nf = 0; nf < 8; ++nf) acc[mf][nf] = (v4f)0.f;

    int lane = tid & 63;
    int wv = tid >> 6;
    int mrow_w = (wv >> 1) * 64;
    int ncol_w = (wv & 1) * 128;
    int lq = lane >> 4, lc = lane & 15;

    for (int ch = 0; ch < 20; ++ch) {
        int c0 = ch * 32 + oct * 8;
        __syncthreads();
#pragma unroll
        for (int pass = 0; pass < 2; ++pass) {
            const float* src = Abase + ((size_t)aqi[pass] * CC + c0) * HW + ap[pass];
            float x[8];
#pragma unroll
            for (int j = 0; j < 8; ++j) x[j] = src[j * HW];
            v8h hi, lo; splitv(x, hi, lo);
            int cell = (arow + pass * 64) * 4 + oct;
            AHI[cell] = hi; ALO[cell] = lo;
        }
#pragma unroll
        for (int pass = 0; pass < 4; ++pass) {
            int nrow = arow + pass * 64;
            const float* src = Bbase + (size_t)c0 * MSP + n0w + nrow;
            float x[8];
#pragma unroll
            for (int j = 0; j < 8; ++j) x[j] = src[j * MSP];
            v8h hi, lo; splitv(x, hi, lo);
            int cell = nrow * 4 + oct;
            BHI[cell] = hi; BLO[cell] = lo;
        }
        __syncthreads();

        v8h ahi[4], alo[4];
#pragma unroll
        for (int mf = 0; mf < 4; ++mf) {
            int idx = (mrow_w + mf * 16 + lc) * 4 + lq;
            ahi[mf] = AHI[idx]; alo[mf] = ALO[idx];
        }
#pragma unroll
        for (int nf = 0; nf < 8; ++nf) {
            int idx = (ncol_w + nf * 16 + lc) * 4 + lq;
            v8h bhi = BHI[idx], blo = BLO[idx];
#pragma unroll
            for (int mf = 0; mf < 4; ++mf) {
                acc[mf][nf] = __builtin_amdgcn_mfma_f32_16x16x32_f16(ahi[mf], bhi, acc[mf][nf], 0, 0, 0);
                acc[mf][nf] = __builtin_amdgcn_mfma_f32_16x16x32_f16(ahi[mf], blo, acc[mf][nf], 0, 0, 0);
                acc[mf][nf] = __builtin_amdgcn_mfma_f32_16x16x32_f16(alo[mf], bhi, acc[mf][nf], 0, 0, 0);
            }
        }
    }

    int chunkidx = (nt & 1) * 2 + (wv & 1);
#pragma unroll
    for (int mf = 0; mf < 4; ++mf) {
#pragma unroll
        for (int r = 0; r < 4; ++r) {
            float v = -__builtin_inff(); int idx = 0x7fffffff;
#pragma unroll
            for (int nf = 0; nf < 8; ++nf) {
                int n_way = n0w + ncol_w + nf * 16 + lc;
                float cv = acc[mf][nf][r];
                if (n_way < MS && cv > v) { v = cv; idx = n_way; }
            }
#pragma unroll
            for (int msk = 1; msk < 16; msk <<= 1) {
                float ov = __shfl_xor(v, msk);
                int oi = __shfl_xor(idx, msk);
                if (ov > v || (ov == v && oi < idx)) { v = ov; idx = oi; }
            }
            if (lc == 0) {
                int mrow = m0 + mrow_w + mf * 16 + lq * 4 + r;
                size_t o = ((size_t)(b * NWAY + w) * 4 + chunkidx) * MPAD + mrow;
                pmax[o] = v; pidx[o] = idx;
            }
        }
    }
}

// ---------------- combine 4 n-chunks, apply invq ----------------
__global__ void combine(const float* __restrict__ pmax, const int* __restrict__ pidx,
                        const float* __restrict__ invq,
                        float* __restrict__ smax, int* __restrict__ sidx) {
    int g = blockIdx.x * 256 + threadIdx.x;
    if (g >= BB * NWAY * MTOT) return;
    int m = g % MTOT; int t = g / MTOT;
    int w = t % NWAY, b = t / NWAY;
    size_t base = ((size_t)(b * NWAY + w) * 4) * MPAD + m;
    float best = pmax[base]; int bi = pidx[base];
#pragma unroll
    for (int c = 1; c < 4; ++c) {
        float v = pmax[base + (size_t)c * MPAD];
        int ii = pidx[base + (size_t)c * MPAD];
        if (v > best) { best = v; bi = ii; }
    }
    int qi = m / HW, p = m % HW;
    size_t o = ((size_t)(b * QQ + qi) * NWAY + w) * HW + p;
    smax[o] = best * invq[b * MTOT + m];
    sidx[o] = bi;
}

// ---------------- finalize ----------------
__global__ void finalize(const float* __restrict__ smax, const int* __restrict__ sidx,
                         const int* __restrict__ qy, float* __restrict__ lossi) {
    int bq = blockIdx.x;
    __shared__ float sm[NWAY][HW];
    __shared__ int   si[NWAY][HW];
    __shared__ float diffv[HW];
    __shared__ int   nearest[HW];
    __shared__ float maskv[HW];
    __shared__ float pred[NWAY];
    int t = threadIdx.x;
    for (int i = t; i < NWAY * HW; i += blockDim.x) {
        sm[i / HW][i % HW] = smax[(size_t)bq * NWAY * HW + i];
        si[i / HW][i % HW] = sidx[(size_t)bq * NWAY * HW + i];
    }
    __syncthreads();
    if (t < HW) {
        float v1 = -INFINITY, v2 = -INFINITY;
        float bestv = -INFINITY; int bestslot = 0;
        for (int w = 0; w < NWAY; ++w) {
            float v = sm[w][t];
            if (v > v1) { v2 = v1; v1 = v; } else if (v > v2) { v2 = v; }
            if (v > bestv) { bestv = v; bestslot = w * MS + si[w][t]; }
        }
        diffv[t] = v1 - v2;
        nearest[t] = bestslot;
    }
    __syncthreads();
    if (t < HW) {
        int slot = nearest[t];
        float bv = (nearest[0] == slot) ? diffv[0] : 0.f;
        int bm = 0;
        for (int m = 1; m < HW; ++m) {
            float val = (nearest[m] == slot) ? diffv[m] : 0.f;
            if (val > bv) { bv = val; bm = m; }
        }
        maskv[t] = (bm == t) ? TEMPER : 0.f;
    }
    __syncthreads();
    if (t < NWAY) {
        float s = 0.f;
        for (int m = 0; m < HW; ++m) s += sm[t][m] * maskv[m];
        pred[t] = s;
    }
    __syncthreads();
    if (t == 0) {
        float mx = pred[0];
        for (int w = 1; w < NWAY; ++w) mx = fmaxf(mx, pred[w]);
        float se = 0.f;
        for (int w = 0; w < NWAY; ++w) se += expf(pred[w] - mx);
        float lse = mx + logf(se);
        int y = qy[bq];
        lossi[bq] = -(pred[y] - lse);
    }
}

__global__ void reduce_loss(const float* __restrict__ lossi, float* __restrict__ out) {
    int t = threadIdx.x;
    float v = 0.f;
    for (int i = t; i < BB * QQ; i += 64) v += lossi[i];
    for (int m = 32; m > 0; m >>= 1) v += __shfl_xor(v, m);
    if (t == 0) out[0] = v / (float)(BB * QQ);
}

extern "C" void kernel_launch(void* const* d_in, const int* in_sizes, int n_in,
                              void* d_out, int out_size, void* d_ws, size_t ws_size,
                              hipStream_t stream) {
    const float* sup = (const float*)d_in[0];   // support_xf (4,25,640,10,10) f32
    const float* qx  = (const float*)d_in[2];   // query_xf   (4,75,640,10,10) f32
    const int*   qy  = (const int*)d_in[3];     // query_y    (4,75) int32
    float* out = (float*)d_out;

    // header region (~6.3 MB)
    float* pmax = (float*)d_ws;                                 // 614400 f
    int*   pidx = (int*)(pmax + (size_t)BB * NWAY * 4 * MPAD);
    float* smax = (float*)(pidx + (size_t)BB * NWAY * 4 * MPAD);
    int*   sidx = (int*)(smax + (size_t)BB * QQ * NWAY * HW);
    float* invq = (float*)(sidx + (size_t)BB * QQ * NWAY * HW);
    float* invs = invq + (size_t)BB * MTOT;                     // 100*HW
    float* lossi = invs + (size_t)BB * 25 * HW;
    char*  big = (char*)(lossi + 512);
    size_t header = (size_t)(big - (char*)d_ws);
    size_t needA = (size_t)BB * MPAD * CC * 2;        // 39.3 MB per array
    size_t needB = (size_t)BB * NWAY * MSP * CC * 2;  // 13.1 MB per array
    size_t need_fast = header + 2 * (needA + needB);

    hipLaunchKernelGGL(norms, dim3(BB * QQ + BB * 25), dim3(256), 0, stream,
                       qx, sup, invq, invs);

    if (ws_size >= need_fast) {
        _Float16* Ahi = (_Float16*)big;
        _Float16* Alo = Ahi + (size_t)BB * MPAD * CC;
        _Float16* Bhi = Alo + (size_t)BB * MPAD * CC;
        _Float16* Blo = Bhi + (size_t)BB * NWAY * MSP * CC;
        hipLaunchKernelGGL(prep_AB, dim3(BB * QQ * 10 + BB * 25 * 10), dim3(256), 0, stream,
                           qx, sup, invs, Ahi, Alo, Bhi, Blo);
        hipLaunchKernelGGL(zero_pad, dim3(1200), dim3(256), 0, stream, Ahi, Alo, Bhi, Blo);
        hipLaunchKernelGGL(simkernel, dim3(BB * 10 * 60), dim3(256), 0, stream,
                           Ahi, Alo, Bhi, Blo, pmax, pidx);
    } else {
        float* snre = (float*)big;   // 26.2 MB
        hipLaunchKernelGGL(norm_support, dim3(BB * 25), dim3(256), 0, stream, sup, snre);
        hipLaunchKernelGGL(simkernel_fb, dim3(BB * 10 * 60), dim3(256), 0, stream,
                           qx, snre, pmax, pidx);
    }
    hipLaunchKernelGGL(combine, dim3((BB * NWAY * MTOT + 255) / 256), dim3(256), 0, stream,
                       pmax, pidx, invq, smax, sidx);
    hipLaunchKernelGGL(finalize, dim3(BB * QQ), dim3(128), 0, stream, smax, sidx, qy, lossi);
    hipLaunchKernelGGL(reduce_loss, dim3(1), dim3(64), 0, stream, lossi, out);
}

// Round 7
// 505.179 us; speedup vs baseline: 1.7908x; 1.3900x over previous
//
#include <hip/hip_runtime.h>
#include <math.h>

#define BB 4
#define QQ 75
#define CC 640
#define HW 100
#define NWAY 5
#define KSHOT 5
#define MS 500
#define MSP 512
#define MTOT 7500
#define MPAD 7680     // 60 tiles of 128
#define TEMPER 2.0f
#define EPSN 1e-8f
#define LB 32768      // bytes per LDS buffer (fast sim)
#define NCH 8         // n-chunks of 64 per way

typedef _Float16 v8h __attribute__((ext_vector_type(8)));
typedef float v4f __attribute__((ext_vector_type(4)));

__device__ inline void splitv(const float* x, v8h& hi, v8h& lo) {
#pragma unroll
    for (int j = 0; j < 8; ++j) {
        _Float16 h = (_Float16)x[j];
        float r0 = x[j] - (float)h;
        hi[j] = h; lo[j] = (_Float16)r0;
    }
}

typedef __attribute__((address_space(3))) unsigned int lds_uint;
typedef __attribute__((address_space(1))) const unsigned int glb_uint;
__device__ inline void gl_lds16(const void* g, void* l) {
    __builtin_amdgcn_global_load_lds((glb_uint*)g, (lds_uint*)l, 16, 0, 0);
}

// ---------------- norms: inverse channel-norms, query (300) + support (100) -----
// Also zeroes out[0] (accumulated by finalize's atomicAdd).
__global__ __launch_bounds__(128) void norms(const float* __restrict__ qx,
                                             const float* __restrict__ sup,
                                             float* __restrict__ invq,
                                             float* __restrict__ invs,
                                             float* __restrict__ out) {
    int bid = blockIdx.x, t = threadIdx.x;
    if (bid == 0 && t == 0) out[0] = 0.f;
    const float* src; float* dst;
    if (bid < BB * QQ) { src = qx + (size_t)bid * CC * HW; dst = invq + bid * HW; }
    else { int bs = bid - BB * QQ; src = sup + (size_t)bs * CC * HW; dst = invs + bs * HW; }
    if (t < HW) {
        float ss = 0.f;
        for (int c = 0; c < CC; ++c) { float v = src[c * HW + t]; ss += v * v; }
        dst[t] = 1.f / (sqrtf(ss) + EPSN);
    }
}

// ---------------- prep_AB: transpose+split one 64-channel chunk per block --------
__global__ __launch_bounds__(256) void prep_AB(const float* __restrict__ qx,
                                               const float* __restrict__ sup,
                                               const float* __restrict__ invs,
                                               _Float16* __restrict__ Ahi,
                                               _Float16* __restrict__ Alo,
                                               _Float16* __restrict__ Bhi,
                                               _Float16* __restrict__ Blo) {
    int g = blockIdx.x;
    const float* src; const float* inv = 0;
    _Float16 *dh, *dl;
    int ct;
    if (g < BB * QQ * 10) {
        int bq = g / 10; ct = g % 10;
        int b = bq / QQ, qi = bq % QQ;
        src = qx + ((size_t)bq * CC + ct * 64) * HW;
        size_t rowbase = (size_t)b * MPAD + qi * HW;
        dh = Ahi + rowbase * CC; dl = Alo + rowbase * CC;
    } else {
        int h = g - BB * QQ * 10;
        int bs = h / 10; ct = h % 10;
        int b = bs / 25, s = bs % 25, w = s / KSHOT, shot = s % KSHOT;
        src = sup + ((size_t)bs * CC + ct * 64) * HW;
        size_t rowbase = (size_t)(b * NWAY + w) * MSP + shot * HW;
        dh = Bhi + rowbase * CC; dl = Blo + rowbase * CC;
        inv = invs + bs * HW;
    }
    __shared__ float tile[64 * 101];   // padded stride 101: transpose reads 2-way max
    __shared__ float invt[HW];
    int t = threadIdx.x;
    if (t < HW) invt[t] = inv ? inv[t] : 1.f;
    for (int i = t; i < 64 * HW; i += 256) tile[(i / HW) * 101 + (i % HW)] = src[i];
    __syncthreads();
    for (int cell = t; cell < 800; cell += 256) {
        int p = cell >> 3, oct = cell & 7;
        float iv = invt[p];
        float x[8];
#pragma unroll
        for (int j = 0; j < 8; ++j) x[j] = tile[(oct * 8 + j) * 101 + p] * iv;
        v8h hi, lo; splitv(x, hi, lo);
        size_t off = (size_t)p * CC + ct * 64 + oct * 8;
        *(v8h*)(dh + off) = hi;
        *(v8h*)(dl + off) = lo;
    }
}

// ---------------- simkernel: dbuf DMA fp16x3 MFMA, 128x128 tile, 2 blocks/CU ----
// Grid: bid = ((b*20 + nt)*60 + mt). nt: way w=nt>>2, n0w=(nt&3)*128.
// 4 waves of 64m x 64n (4x4 16x16x32 frags). LDS 2 x 32 KB.
// No zero-pad needed: ws poison 0xAA is a finite f16; pad m-rows never read,
// pad n-cols masked by n<MS.
__global__ __launch_bounds__(256, 2) void simkernel(
        const _Float16* __restrict__ Ahi, const _Float16* __restrict__ Alo,
        const _Float16* __restrict__ Bhi, const _Float16* __restrict__ Blo,
        float* __restrict__ pmax, unsigned short* __restrict__ pidx) {
    __shared__ char lds_raw[2 * LB];

    int bid = blockIdx.x;
    int mt = bid % 60; int t2 = bid / 60;
    int nt = t2 % 20;  int b = t2 / 20;
    int m0 = mt * 128;
    int w = nt >> 2, n0w = (nt & 3) * 128;

    int tid = threadIdx.x;
    int lane = tid & 63;
    int wvu = __builtin_amdgcn_readfirstlane(tid >> 6);

    const char* abase[4];
    abase[0] = (const char*)(Ahi + ((size_t)b * MPAD + m0) * CC);
    abase[1] = (const char*)(Alo + ((size_t)b * MPAD + m0) * CC);
    abase[2] = (const char*)(Bhi + ((size_t)(b * NWAY + w) * MSP + n0w) * CC);
    abase[3] = (const char*)(Blo + ((size_t)(b * NWAY + w) * MSP + n0w) * CC);

    // per-lane gather: row r=lane>>2 within 16-row segment, swizzled octet
    int rr0 = lane >> 2;
    int oct = (lane & 3) ^ ((lane >> 3) & 3);
    int laneoff = rr0 * (CC * 2) + oct * 16;

    const char* segsrc[8];
    int segoff[8];
#pragma unroll
    for (int s = 0; s < 8; ++s) {
        int g = wvu * 8 + s;            // 0..31: 8 segments per array
        segsrc[s] = abase[g >> 3] + (size_t)((g & 7) * 16) * (CC * 2) + laneoff;
        segoff[s] = g * 1024;
    }

    int wv = tid >> 6;
    int mrow_w = (wv >> 1) * 64;
    int ncol_w = (wv & 1) * 64;
    int lq = lane >> 4, lc = lane & 15;

    int idxA[4], idxB[4];
#pragma unroll
    for (int mf = 0; mf < 4; ++mf) {
        int row = mrow_w + mf * 16 + lc;
        idxA[mf] = row * 4 + (lq ^ ((row >> 1) & 3));
    }
#pragma unroll
    for (int nf = 0; nf < 4; ++nf) {
        int row = ncol_w + nf * 16 + lc;
        idxB[nf] = row * 4 + (lq ^ ((row >> 1) & 3));
    }

    v4f acc[4][4];
#pragma unroll
    for (int mf = 0; mf < 4; ++mf)
#pragma unroll
        for (int nf = 0; nf < 4; ++nf) acc[mf][nf] = (v4f)0.f;

    // prologue: DMA chunk 0 into half 0
#pragma unroll
    for (int s = 0; s < 8; ++s)
        gl_lds16(segsrc[s], lds_raw + segoff[s]);

    for (int ch = 0; ch < 20; ++ch) {
        __syncthreads();              // drains DMA(ch); fences compute(ch-1) reads
        if (ch < 19) {                // prefetch next chunk into the other half
            int choff = (ch + 1) * 64;
            int dbase = ((ch + 1) & 1) * LB;
#pragma unroll
            for (int s = 0; s < 8; ++s)
                gl_lds16(segsrc[s] + choff, lds_raw + dbase + segoff[s]);
        }
        char* cbuf = lds_raw + (ch & 1) * LB;
        v8h* AHI = (v8h*)cbuf;
        v8h* ALO = (v8h*)(cbuf + 8192);
        v8h* BHI = (v8h*)(cbuf + 16384);
        v8h* BLO = (v8h*)(cbuf + 24576);

        v8h ahi[4], alo[4];
#pragma unroll
        for (int mf = 0; mf < 4; ++mf) { ahi[mf] = AHI[idxA[mf]]; alo[mf] = ALO[idxA[mf]]; }
#pragma unroll
        for (int nf = 0; nf < 4; ++nf) {
            v8h bhi = BHI[idxB[nf]], blo = BLO[idxB[nf]];
#pragma unroll
            for (int mf = 0; mf < 4; ++mf) {
                acc[mf][nf] = __builtin_amdgcn_mfma_f32_16x16x32_f16(ahi[mf], bhi, acc[mf][nf], 0, 0, 0);
                acc[mf][nf] = __builtin_amdgcn_mfma_f32_16x16x32_f16(ahi[mf], blo, acc[mf][nf], 0, 0, 0);
                acc[mf][nf] = __builtin_amdgcn_mfma_f32_16x16x32_f16(alo[mf], bhi, acc[mf][nf], 0, 0, 0);
            }
        }
    }

    int chunk = (nt & 3) * 2 + (wv & 1);        // 64-col chunk index, ascending n
#pragma unroll
    for (int mf = 0; mf < 4; ++mf) {
#pragma unroll
        for (int r = 0; r < 4; ++r) {
            float v = -__builtin_inff(); int idx = 0x7fffffff;
#pragma unroll
            for (int nf = 0; nf < 4; ++nf) {
                int n_way = n0w + ncol_w + nf * 16 + lc;
                float cv = acc[mf][nf][r];
                if (n_way < MS && cv > v) { v = cv; idx = n_way; }
            }
#pragma unroll
            for (int msk = 1; msk < 16; msk <<= 1) {
                float ov = __shfl_xor(v, msk);
                int oi = __shfl_xor(idx, msk);
                if (ov > v || (ov == v && oi < idx)) { v = ov; idx = oi; }
            }
            if (lc == 0) {
                int mrow = m0 + mrow_w + mf * 16 + lq * 4 + r;
                size_t o = ((size_t)(b * NWAY + w) * NCH + chunk) * MPAD + mrow;
                pmax[o] = v;
                pidx[o] = (unsigned short)(idx & 0xffff);
            }
        }
    }
}

// ================= FALLBACK PATH (ws too small) =================
__global__ void norm_support(const float* __restrict__ sup, float* __restrict__ snre) {
    int bid = blockIdx.x;
    int b = bid / 25, s = bid % 25;
    int w = s / KSHOT, shot = s % KSHOT;
    const float* src = sup + (size_t)bid * CC * HW;
    float* dst = snre + ((size_t)(b * NWAY + w)) * CC * MSP + shot * HW;
    __shared__ float inv[HW];
    int t = threadIdx.x;
    if (t < HW) {
        float ss = 0.f;
        for (int c = 0; c < CC; ++c) { float v = src[c * HW + t]; ss += v * v; }
        inv[t] = 1.f / (sqrtf(ss) + EPSN);
    }
    __syncthreads();
    for (int i = t; i < CC * HW; i += 256) {
        int c = i / HW, p = i % HW;
        dst[c * MSP + p] = src[i] * inv[p];
    }
    if (shot == KSHOT - 1) {
        float* padbase = snre + ((size_t)(b * NWAY + w)) * CC * MSP;
        for (int i = t; i < CC * (MSP - MS); i += 256) {
            int c = i / (MSP - MS), j = i % (MSP - MS);
            padbase[c * MSP + MS + j] = 0.f;
        }
    }
}

__global__ __launch_bounds__(256) void simkernel_fb(
        const float* __restrict__ qx, const float* __restrict__ snre,
        float* __restrict__ pmax, unsigned short* __restrict__ pidx) {
    __shared__ char lds_fb[49152];
    v8h* AHI = (v8h*)(lds_fb);
    v8h* ALO = (v8h*)(lds_fb + 8192);
    v8h* BHI = (v8h*)(lds_fb + 16384);
    v8h* BLO = (v8h*)(lds_fb + 32768);

    int bid = blockIdx.x;
    int mt = bid % 60; int t2 = bid / 60;
    int nt = t2 % 10;  int b = t2 / 10;
    int m0 = mt * 128;
    int w = nt >> 1;
    int n0w = (nt & 1) * 256;

    int tid = threadIdx.x;
    const float* Abase = qx + (size_t)b * QQ * CC * HW;
    const float* Bbase = snre + (size_t)(b * NWAY + w) * CC * MSP;

    int oct = tid & 3;
    int arow = tid >> 2;
    int aqi[2], ap[2];
#pragma unroll
    for (int pass = 0; pass < 2; ++pass) {
        int mg = m0 + arow + pass * 64;
        if (mg >= MTOT) mg = 0;
        aqi[pass] = mg / HW; ap[pass] = mg % HW;
    }

    v4f acc[4][8];
#pragma unroll
    for (int mf = 0; mf < 4; ++mf)
#pragma unroll
        for (int nf = 0; nf < 8; ++nf) acc[mf][nf] = (v4f)0.f;

    int lane = tid & 63;
    int wv = tid >> 6;
    int mrow_w = (wv >> 1) * 64;
    int ncol_w = (wv & 1) * 128;
    int lq = lane >> 4, lc = lane & 15;

    for (int ch = 0; ch < 20; ++ch) {
        int c0 = ch * 32 + oct * 8;
        __syncthreads();
#pragma unroll
        for (int pass = 0; pass < 2; ++pass) {
            const float* src = Abase + ((size_t)aqi[pass] * CC + c0) * HW + ap[pass];
            float x[8];
#pragma unroll
            for (int j = 0; j < 8; ++j) x[j] = src[j * HW];
            v8h hi, lo; splitv(x, hi, lo);
            int cell = (arow + pass * 64) * 4 + oct;
            AHI[cell] = hi; ALO[cell] = lo;
        }
#pragma unroll
        for (int pass = 0; pass < 4; ++pass) {
            int nrow = arow + pass * 64;
            const float* src = Bbase + (size_t)c0 * MSP + n0w + nrow;
            float x[8];
#pragma unroll
            for (int j = 0; j < 8; ++j) x[j] = src[j * MSP];
            v8h hi, lo; splitv(x, hi, lo);
            int cell = nrow * 4 + oct;
            BHI[cell] = hi; BLO[cell] = lo;
        }
        __syncthreads();

        v8h ahi[4], alo[4];
#pragma unroll
        for (int mf = 0; mf < 4; ++mf) {
            int idx = (mrow_w + mf * 16 + lc) * 4 + lq;
            ahi[mf] = AHI[idx]; alo[mf] = ALO[idx];
        }
#pragma unroll
        for (int nf = 0; nf < 8; ++nf) {
            int idx = (ncol_w + nf * 16 + lc) * 4 + lq;
            v8h bhi = BHI[idx], blo = BLO[idx];
#pragma unroll
            for (int mf = 0; mf < 4; ++mf) {
                acc[mf][nf] = __builtin_amdgcn_mfma_f32_16x16x32_f16(ahi[mf], bhi, acc[mf][nf], 0, 0, 0);
                acc[mf][nf] = __builtin_amdgcn_mfma_f32_16x16x32_f16(ahi[mf], blo, acc[mf][nf], 0, 0, 0);
                acc[mf][nf] = __builtin_amdgcn_mfma_f32_16x16x32_f16(alo[mf], bhi, acc[mf][nf], 0, 0, 0);
            }
        }
    }

    int chunkidx = (nt & 1) * 2 + (wv & 1);   // 128-col chunk of the way
#pragma unroll
    for (int mf = 0; mf < 4; ++mf) {
#pragma unroll
        for (int r = 0; r < 4; ++r) {
            float v = -__builtin_inff(); int idx = 0x7fffffff;
#pragma unroll
            for (int nf = 0; nf < 8; ++nf) {
                int n_way = n0w + ncol_w + nf * 16 + lc;
                float cv = acc[mf][nf][r];
                if (n_way < MS && cv > v) { v = cv; idx = n_way; }
            }
#pragma unroll
            for (int msk = 1; msk < 16; msk <<= 1) {
                float ov = __shfl_xor(v, msk);
                int oi = __shfl_xor(idx, msk);
                if (ov > v || (ov == v && oi < idx)) { v = ov; idx = oi; }
            }
            if (lc == 0) {
                int mrow = m0 + mrow_w + mf * 16 + lq * 4 + r;
                size_t ob = (size_t)(b * NWAY + w) * NCH * MPAD + mrow;
                int s_hi = (idx != 0x7fffffff) ? (idx >> 6) : -1;  // 64-col slot
#pragma unroll
                for (int sl2 = 0; sl2 < 2; ++sl2) {
                    int sl = chunkidx * 2 + sl2;
                    if (sl == s_hi) {
                        pmax[ob + (size_t)sl * MPAD] = v;
                        pidx[ob + (size_t)sl * MPAD] = (unsigned short)(idx & 0xffff);
                    } else {
                        pmax[ob + (size_t)sl * MPAD] = -__builtin_inff();
                        pidx[ob + (size_t)sl * MPAD] = 0xffffu;
                    }
                }
            }
        }
    }
}

// ------- finalize: combine chunks + top-2 diff + mutual mask + predict + NLL -----
__global__ __launch_bounds__(128) void finalize(
        const float* __restrict__ pmax, const unsigned short* __restrict__ pidx,
        const float* __restrict__ invq, const int* __restrict__ qy,
        float* __restrict__ out) {
    int bq = blockIdx.x;
    int b = bq / QQ, qi = bq % QQ;
    __shared__ float sm[NWAY][HW];
    __shared__ int   si[NWAY][HW];
    __shared__ float diffv[HW];
    __shared__ int   nearest[HW];
    __shared__ float maskv[HW];
    __shared__ float pred[NWAY];
    int t = threadIdx.x;
    if (t < HW) {
        float iq = invq[bq * HW + t];
        for (int w = 0; w < NWAY; ++w) {
            size_t base = ((size_t)(b * NWAY + w) * NCH) * MPAD + qi * HW + t;
            float best = -__builtin_inff(); int bi = 0x7fffffff;
            for (int c = 0; c < NCH; ++c) {
                float v = pmax[base + (size_t)c * MPAD];
                if (v > best) { best = v; bi = pidx[base + (size_t)c * MPAD]; }
            }
            sm[w][t] = best * iq;
            si[w][t] = bi;
        }
    }
    __syncthreads();
    if (t < HW) {
        float v1 = -INFINITY, v2 = -INFINITY;
        float bestv = -INFINITY; int bestslot = 0;
        for (int w = 0; w < NWAY; ++w) {
            float v = sm[w][t];
            if (v > v1) { v2 = v1; v1 = v; } else if (v > v2) { v2 = v; }
            if (v > bestv) { bestv = v; bestslot = w * MS + si[w][t]; }
        }
        diffv[t] = v1 - v2;
        nearest[t] = bestslot;
    }
    __syncthreads();
    if (t < HW) {
        int slot = nearest[t];
        float bv = (nearest[0] == slot) ? diffv[0] : 0.f;
        int bm = 0;
        for (int m = 1; m < HW; ++m) {
            float val = (nearest[m] == slot) ? diffv[m] : 0.f;
            if (val > bv) { bv = val; bm = m; }
        }
        maskv[t] = (bm == t) ? TEMPER : 0.f;
    }
    __syncthreads();
    if (t < NWAY) {
        float s = 0.f;
        for (int m = 0; m < HW; ++m) s += sm[t][m] * maskv[m];
        pred[t] = s;
    }
    __syncthreads();
    if (t == 0) {
        float mx = pred[0];
        for (int w = 1; w < NWAY; ++w) mx = fmaxf(mx, pred[w]);
        float se = 0.f;
        for (int w = 0; w < NWAY; ++w) se += expf(pred[w] - mx);
        float lse = mx + logf(se);
        int y = qy[bq];
        atomicAdd(out, -(pred[y] - lse) * (1.f / (BB * QQ)));
    }
}

extern "C" void kernel_launch(void* const* d_in, const int* in_sizes, int n_in,
                              void* d_out, int out_size, void* d_ws, size_t ws_size,
                              hipStream_t stream) {
    const float* sup = (const float*)d_in[0];   // support_xf (4,25,640,10,10) f32
    const float* qx  = (const float*)d_in[2];   // query_xf   (4,75,640,10,10) f32
    const int*   qy  = (const int*)d_in[3];     // query_y    (4,75) int32
    float* out = (float*)d_out;

    // header region (~7.5 MB)
    size_t pcount = (size_t)BB * NWAY * NCH * MPAD;     // 1,228,800
    float* pmax = (float*)d_ws;
    unsigned short* pidx = (unsigned short*)(pmax + pcount);
    float* invq = (float*)(pidx + pcount);
    float* invs = invq + (size_t)BB * MTOT;             // actually BB*QQ*HW == BB*MTOT
    char*  big = (char*)(invs + (size_t)BB * 25 * HW);
    size_t header = (size_t)(big - (char*)d_ws);
    size_t needA = (size_t)BB * MPAD * CC * 2;          // 39.3 MB per array
    size_t needB = (size_t)BB * NWAY * MSP * CC * 2;    // 13.1 MB per array
    size_t need_fast = header + 2 * (needA + needB);

    hipLaunchKernelGGL(norms, dim3(BB * QQ + BB * 25), dim3(128), 0, stream,
                       qx, sup, invq, invs, out);

    if (ws_size >= need_fast) {
        _Float16* Ahi = (_Float16*)big;
        _Float16* Alo = Ahi + (size_t)BB * MPAD * CC;
        _Float16* Bhi = Alo + (size_t)BB * MPAD * CC;
        _Float16* Blo = Bhi + (size_t)BB * NWAY * MSP * CC;
        hipLaunchKernelGGL(prep_AB, dim3(BB * QQ * 10 + BB * 25 * 10), dim3(256), 0, stream,
                           qx, sup, invs, Ahi, Alo, Bhi, Blo);
        hipLaunchKernelGGL(simkernel, dim3(BB * 20 * 60), dim3(256), 0, stream,
                           Ahi, Alo, Bhi, Blo, pmax, pidx);
    } else {
        float* snre = (float*)big;   // 26.2 MB
        hipLaunchKernelGGL(norm_support, dim3(BB * 25), dim3(256), 0, stream, sup, snre);
        hipLaunchKernelGGL(simkernel_fb, dim3(BB * 10 * 60), dim3(256), 0, stream,
                           qx, snre, pmax, pidx);
    }
    hipLaunchKernelGGL(finalize, dim3(BB * QQ), dim3(128), 0, stream,
                       pmax, pidx, invq, qy, out);
}